// Round 1
// baseline (2239.181 us; speedup 1.0000x reference)
//
#include <hip/hip_runtime.h>
#include <math.h>

#define IN_CH 128
#define HID 64
#define OUT_CH 10

// ---------------- scatter: agg[dst] += x[src], 128 channels ----------------
__global__ __launch_bounds__(256) void k_scatter128(
    const float4* __restrict__ x4, const int* __restrict__ src,
    const int* __restrict__ dst, float* __restrict__ agg, int E)
{
    int tid = blockIdx.x * 256 + threadIdx.x;
    int e = tid >> 5;               // 32 lanes per edge, 4 ch each
    if (e >= E) return;
    int lane = tid & 31;
    int s = src[e], d = dst[e];
    float4 v = x4[(long)s * 32 + lane];
    float* p = agg + (long)d * 128 + lane * 4;
    atomicAdd(p + 0, v.x);
    atomicAdd(p + 1, v.y);
    atomicAdd(p + 2, v.z);
    atomicAdd(p + 3, v.w);
}

// ---------------- scatter: agg[dst] += h[src], 64 channels ----------------
__global__ __launch_bounds__(256) void k_scatter64(
    const float4* __restrict__ h4, const int* __restrict__ src,
    const int* __restrict__ dst, float* __restrict__ agg, int E)
{
    int tid = blockIdx.x * 256 + threadIdx.x;
    int e = tid >> 4;               // 16 lanes per edge, 4 ch each
    if (e >= E) return;
    int lane = tid & 15;
    int s = src[e], d = dst[e];
    float4 v = h4[(long)s * 16 + lane];
    float* p = agg + (long)d * 64 + lane * 4;
    atomicAdd(p + 0, v.x);
    atomicAdd(p + 1, v.y);
    atomicAdd(p + 2, v.z);
    atomicAdd(p + 3, v.w);
}

// ---------------- GIN MLP layer 0: t=(1+eps)x+agg; relu(t@wa+ba); relu(.@wb+bb)
__global__ __launch_bounds__(256) void k_mlp0(
    const float* __restrict__ x, const float* __restrict__ agg,
    const float* __restrict__ epsp,
    const float* __restrict__ wa, const float* __restrict__ ba,
    const float* __restrict__ wb, const float* __restrict__ bb,
    float* __restrict__ out, int N)
{
    __shared__ float lwa[IN_CH * HID];   // 32 KB
    __shared__ float lwb[HID * HID];     // 16 KB
    __shared__ float t[4][IN_CH];
    __shared__ float hb[4][HID];
    int tid = threadIdx.x;
    for (int i = tid; i < IN_CH * HID; i += 256) lwa[i] = wa[i];
    for (int i = tid; i < HID * HID; i += 256) lwb[i] = wb[i];
    float e = 1.0f + epsp[0];
    int n = tid >> 6, c = tid & 63;
    float bias_a = ba[c], bias_b = bb[c];
    __syncthreads();
    for (int g0 = blockIdx.x * 4; g0 < N; g0 += gridDim.x * 4) {
        for (int i = tid; i < 4 * IN_CH; i += 256) {
            int nn = i >> 7, k = i & (IN_CH - 1);
            int node = g0 + nn;
            if (node < N)
                t[nn][k] = e * x[(long)node * IN_CH + k] + agg[(long)node * IN_CH + k];
        }
        __syncthreads();
        float acc = bias_a;
        #pragma unroll
        for (int k = 0; k < IN_CH; k++) acc = fmaf(t[n][k], lwa[k * HID + c], acc);
        hb[n][c] = fmaxf(acc, 0.0f);
        __syncthreads();
        float acc2 = bias_b;
        #pragma unroll
        for (int k = 0; k < HID; k++) acc2 = fmaf(hb[n][k], lwb[k * HID + c], acc2);
        int node = g0 + n;
        if (node < N) out[(long)node * HID + c] = fmaxf(acc2, 0.0f);
        __syncthreads();
    }
}

// ---------------- GIN MLP layer 1 (64->64->64) fused with graph pooling ----
__global__ __launch_bounds__(256) void k_mlp1(
    const float* __restrict__ x, const float* __restrict__ agg,
    const float* __restrict__ epsp,
    const float* __restrict__ wa, const float* __restrict__ ba,
    const float* __restrict__ wb, const float* __restrict__ bb,
    const int* __restrict__ batch, float* __restrict__ pooled, int N)
{
    __shared__ float lwa[HID * HID];
    __shared__ float lwb[HID * HID];
    __shared__ float t[4][HID];
    __shared__ float hb[4][HID];
    int tid = threadIdx.x;
    for (int i = tid; i < HID * HID; i += 256) { lwa[i] = wa[i]; lwb[i] = wb[i]; }
    float e = 1.0f + epsp[0];
    int n = tid >> 6, c = tid & 63;
    float bias_a = ba[c], bias_b = bb[c];
    __syncthreads();
    for (int g0 = blockIdx.x * 4; g0 < N; g0 += gridDim.x * 4) {
        int node_l = g0 + (tid >> 6);
        {
            int nn = tid >> 6, k = tid & 63;  // 256 threads = 4 nodes x 64 ch
            int node = g0 + nn;
            if (node < N)
                t[nn][k] = e * x[(long)node * HID + k] + agg[(long)node * HID + k];
        }
        __syncthreads();
        float acc = bias_a;
        #pragma unroll
        for (int k = 0; k < HID; k++) acc = fmaf(t[n][k], lwa[k * HID + c], acc);
        hb[n][c] = fmaxf(acc, 0.0f);
        __syncthreads();
        float acc2 = bias_b;
        #pragma unroll
        for (int k = 0; k < HID; k++) acc2 = fmaf(hb[n][k], lwb[k * HID + c], acc2);
        acc2 = fmaxf(acc2, 0.0f);
        if (node_l < N)
            atomicAdd(&pooled[(long)batch[node_l] * HID + c], acc2);
        __syncthreads();
    }
}

// ---------------- head: logits = pooled@fcw+fcb; log_softmax ----------------
__global__ __launch_bounds__(64) void k_head(
    const float* __restrict__ pooled, const float* __restrict__ fcw,
    const float* __restrict__ fcb, float* __restrict__ out)
{
    int g = blockIdx.x;
    int l = threadIdx.x;
    float logit = -INFINITY;
    if (l < OUT_CH) {
        float acc = fcb[l];
        #pragma unroll
        for (int k = 0; k < HID; k++)
            acc = fmaf(pooled[g * HID + k], fcw[k * OUT_CH + l], acc);
        logit = acc;
    }
    float m = logit;
    #pragma unroll
    for (int off = 32; off; off >>= 1) m = fmaxf(m, __shfl_xor(m, off));
    float ex = (l < OUT_CH) ? expf(logit - m) : 0.0f;
    float s = ex;
    #pragma unroll
    for (int off = 32; off; off >>= 1) s += __shfl_xor(s, off);
    if (l < OUT_CH) out[g * OUT_CH + l] = logit - m - logf(s);
}

extern "C" void kernel_launch(void* const* d_in, const int* in_sizes, int n_in,
                              void* d_out, int out_size, void* d_ws, size_t ws_size,
                              hipStream_t stream) {
    const float* x    = (const float*)d_in[0];
    const int*   ei   = (const int*)d_in[1];
    const int*   batch= (const int*)d_in[2];
    const float* eps0 = (const float*)d_in[3];
    const float* w0a  = (const float*)d_in[4];
    const float* b0a  = (const float*)d_in[5];
    const float* w0b  = (const float*)d_in[6];
    const float* b0b  = (const float*)d_in[7];
    const float* eps1 = (const float*)d_in[8];
    const float* w1a  = (const float*)d_in[9];
    const float* b1a  = (const float*)d_in[10];
    const float* w1b  = (const float*)d_in[11];
    const float* b1b  = (const float*)d_in[12];
    const float* fcw  = (const float*)d_in[13];
    const float* fcb  = (const float*)d_in[14];
    float* out = (float*)d_out;

    const int N = in_sizes[0] / IN_CH;       // 50000
    const int E = in_sizes[1] / 2;           // 800000
    const int G = out_size / OUT_CH;         // 512
    const int* src = ei;
    const int* dst = ei + E;

    // workspace layout (floats)
    float* agg0   = (float*)d_ws;                       // N*128
    float* h0     = agg0 + (long)N * IN_CH;             // N*64
    float* agg1   = h0   + (long)N * HID;               // N*64
    float* pooled = agg1 + (long)N * HID;               // G*64

    hipMemsetAsync(agg0, 0, (size_t)N * IN_CH * sizeof(float), stream);
    hipMemsetAsync(agg1, 0, (size_t)N * HID * sizeof(float), stream);
    hipMemsetAsync(pooled, 0, (size_t)G * HID * sizeof(float), stream);

    k_scatter128<<<(E * 32 + 255) / 256, 256, 0, stream>>>(
        (const float4*)x, src, dst, agg0, E);

    k_mlp0<<<1024, 256, 0, stream>>>(x, agg0, eps0, w0a, b0a, w0b, b0b, h0, N);

    k_scatter64<<<(E * 16 + 255) / 256, 256, 0, stream>>>(
        (const float4*)h0, src, dst, agg1, E);

    k_mlp1<<<1024, 256, 0, stream>>>(h0, agg1, eps1, w1a, b1a, w1b, b1b,
                                     batch, pooled, N);

    k_head<<<G, 64, 0, stream>>>(pooled, fcw, fcb, out);
}

// Round 2
// 673.955 us; speedup vs baseline: 3.3224x; 3.3224x over previous
//
#include <hip/hip_runtime.h>
#include <math.h>

#define IN_CH 128
#define HID 64
#define OUT_CH 10

// ---------- CSR build: degree count ----------
__global__ __launch_bounds__(256) void k_count(
    const int* __restrict__ dst, int* __restrict__ cnt, int E)
{
    int e = blockIdx.x * 256 + threadIdx.x;
    if (e < E) atomicAdd(&cnt[dst[e]], 1);
}

// ---------- CSR build: exclusive scan of cnt[N] -> row_ptr[N+1] ----------
// single block, 1024 threads, chunked: local seq sum -> block scan -> write back
__global__ __launch_bounds__(1024) void k_scan(
    const int* __restrict__ cnt, int* __restrict__ row_ptr, int N)
{
    __shared__ int lds[1024];
    int tid = threadIdx.x;
    int chunk = (N + 1023) >> 10;
    long start = (long)tid * chunk;
    int s = 0;
    for (int i = 0; i < chunk; i++) {
        long idx = start + i;
        if (idx < N) s += cnt[idx];
    }
    lds[tid] = s;
    __syncthreads();
    // Hillis-Steele inclusive scan
    for (int off = 1; off < 1024; off <<= 1) {
        int t = (tid >= off) ? lds[tid - off] : 0;
        __syncthreads();
        lds[tid] += t;
        __syncthreads();
    }
    int run = lds[tid] - s;   // exclusive prefix of this thread's chunk
    for (int i = 0; i < chunk; i++) {
        long idx = start + i;
        if (idx < N) { row_ptr[idx] = run; run += cnt[idx]; }
    }
    if (tid == 1023) row_ptr[N] = lds[1023];
}

// ---------- CSR build: place edges ----------
__global__ __launch_bounds__(256) void k_place(
    const int* __restrict__ src, const int* __restrict__ dst,
    const int* __restrict__ row_ptr, int* __restrict__ fill,
    int* __restrict__ col, int E)
{
    int e = blockIdx.x * 256 + threadIdx.x;
    if (e >= E) return;
    int d = dst[e];
    int pos = atomicAdd(&fill[d], 1);
    col[row_ptr[d] + pos] = src[e];
}

// ---------- layer 0: CSR gather + (1+eps)x + MLP(128->64->64), all fused ----
__global__ __launch_bounds__(256) void k_gmlp0(
    const float2* __restrict__ x2, const int* __restrict__ row_ptr,
    const int* __restrict__ col, const float* __restrict__ epsp,
    const float* __restrict__ wa, const float* __restrict__ ba,
    const float* __restrict__ wb, const float* __restrict__ bb,
    float* __restrict__ h0, int N)
{
    __shared__ float lwa[IN_CH * HID];   // 32 KB
    __shared__ float lwb[HID * HID];     // 16 KB
    __shared__ float t[4][IN_CH];
    __shared__ float hb[4][HID];
    int tid = threadIdx.x;
    for (int i = tid; i < IN_CH * HID; i += 256) lwa[i] = wa[i];
    for (int i = tid; i < HID * HID; i += 256) lwb[i] = wb[i];
    float e = 1.0f + epsp[0];
    int n = tid >> 6, c = tid & 63;      // wave n handles node g0+n; c = lane
    float bias_a = ba[c], bias_b = bb[c];
    __syncthreads();
    for (int g0 = blockIdx.x * 4; g0 < N; g0 += gridDim.x * 4) {
        int node = g0 + n;
        float2 acc = make_float2(0.f, 0.f);
        if (node < N) {
            int rs = row_ptr[node], re = row_ptr[node + 1];
            for (int j = rs; j < re; j++) {
                int s = col[j];
                float2 v = x2[(long)s * 64 + c];   // channels 2c, 2c+1
                acc.x += v.x; acc.y += v.y;
            }
            float2 xv = x2[(long)node * 64 + c];
            acc.x += e * xv.x; acc.y += e * xv.y;
        }
        t[n][2 * c] = acc.x; t[n][2 * c + 1] = acc.y;
        __syncthreads();
        float a1 = bias_a;
        #pragma unroll
        for (int k = 0; k < IN_CH; k++) a1 = fmaf(t[n][k], lwa[k * HID + c], a1);
        hb[n][c] = fmaxf(a1, 0.f);
        __syncthreads();
        float a2 = bias_b;
        #pragma unroll
        for (int k = 0; k < HID; k++) a2 = fmaf(hb[n][k], lwb[k * HID + c], a2);
        if (node < N) h0[(long)node * HID + c] = fmaxf(a2, 0.f);
        __syncthreads();
    }
}

// ---------- layer 1: CSR gather + MLP(64->64->64) + graph pooling, fused ----
__global__ __launch_bounds__(256) void k_gmlp1(
    const float* __restrict__ h0, const int* __restrict__ row_ptr,
    const int* __restrict__ col, const float* __restrict__ epsp,
    const float* __restrict__ wa, const float* __restrict__ ba,
    const float* __restrict__ wb, const float* __restrict__ bb,
    const int* __restrict__ batch, float* __restrict__ pooled, int N)
{
    __shared__ float lwa[HID * HID];
    __shared__ float lwb[HID * HID];
    __shared__ float t[4][HID];
    __shared__ float hb[4][HID];
    __shared__ float red[4][HID];
    int tid = threadIdx.x;
    for (int i = tid; i < HID * HID; i += 256) { lwa[i] = wa[i]; lwb[i] = wb[i]; }
    float e = 1.0f + epsp[0];
    int n = tid >> 6, c = tid & 63;
    float bias_a = ba[c], bias_b = bb[c];
    __syncthreads();
    for (int g0 = blockIdx.x * 4; g0 < N; g0 += gridDim.x * 4) {
        int node = g0 + n;
        float acc = 0.f;
        if (node < N) {
            int rs = row_ptr[node], re = row_ptr[node + 1];
            for (int j = rs; j < re; j++)
                acc += h0[(long)col[j] * HID + c];
            acc += e * h0[(long)node * HID + c];
        }
        t[n][c] = acc;
        __syncthreads();
        float a1 = bias_a;
        #pragma unroll
        for (int k = 0; k < HID; k++) a1 = fmaf(t[n][k], lwa[k * HID + c], a1);
        hb[n][c] = fmaxf(a1, 0.f);
        __syncthreads();
        float a2 = bias_b;
        #pragma unroll
        for (int k = 0; k < HID; k++) a2 = fmaf(hb[n][k], lwb[k * HID + c], a2);
        red[n][c] = (node < N) ? fmaxf(a2, 0.f) : 0.f;
        __syncthreads();
        // pooled += : batch is sorted, so 4 consecutive nodes usually share a graph
        if (n == 0) {
            int nv = min(4, N - g0);
            int b0 = batch[g0], bl = batch[g0 + nv - 1];
            if (b0 == bl) {
                float s = 0.f;
                for (int nn = 0; nn < nv; nn++) s += red[nn][c];
                atomicAdd(&pooled[(long)b0 * HID + c], s);
            } else {
                for (int nn = 0; nn < nv; nn++)
                    atomicAdd(&pooled[(long)batch[g0 + nn] * HID + c], red[nn][c]);
            }
        }
        __syncthreads();
    }
}

// ---------- head: logits = pooled@fcw+fcb; log_softmax ----------
__global__ __launch_bounds__(64) void k_head(
    const float* __restrict__ pooled, const float* __restrict__ fcw,
    const float* __restrict__ fcb, float* __restrict__ out)
{
    int g = blockIdx.x;
    int l = threadIdx.x;
    float logit = -INFINITY;
    if (l < OUT_CH) {
        float acc = fcb[l];
        #pragma unroll
        for (int k = 0; k < HID; k++)
            acc = fmaf(pooled[g * HID + k], fcw[k * OUT_CH + l], acc);
        logit = acc;
    }
    float m = logit;
    #pragma unroll
    for (int off = 32; off; off >>= 1) m = fmaxf(m, __shfl_xor(m, off));
    float ex = (l < OUT_CH) ? expf(logit - m) : 0.0f;
    float s = ex;
    #pragma unroll
    for (int off = 32; off; off >>= 1) s += __shfl_xor(s, off);
    if (l < OUT_CH) out[g * OUT_CH + l] = logit - m - logf(s);
}

extern "C" void kernel_launch(void* const* d_in, const int* in_sizes, int n_in,
                              void* d_out, int out_size, void* d_ws, size_t ws_size,
                              hipStream_t stream) {
    const float* x    = (const float*)d_in[0];
    const int*   ei   = (const int*)d_in[1];
    const int*   batch= (const int*)d_in[2];
    const float* eps0 = (const float*)d_in[3];
    const float* w0a  = (const float*)d_in[4];
    const float* b0a  = (const float*)d_in[5];
    const float* w0b  = (const float*)d_in[6];
    const float* b0b  = (const float*)d_in[7];
    const float* eps1 = (const float*)d_in[8];
    const float* w1a  = (const float*)d_in[9];
    const float* b1a  = (const float*)d_in[10];
    const float* w1b  = (const float*)d_in[11];
    const float* b1b  = (const float*)d_in[12];
    const float* fcw  = (const float*)d_in[13];
    const float* fcb  = (const float*)d_in[14];
    float* out = (float*)d_out;

    const int N = in_sizes[0] / IN_CH;       // 50000
    const int E = in_sizes[1] / 2;           // 800000
    const int G = out_size / OUT_CH;         // 512
    const int* src = ei;
    const int* dst = ei + E;

    // workspace layout (bytes, 16B-aligned blocks)
    char* ws = (char*)d_ws;
    int*   cnt     = (int*)(ws);                         // N ints      @0
    int*   fill    = (int*)(ws + 200000);                // N ints
    int*   row_ptr = (int*)(ws + 400000);                // N+1 ints (padded to 200016)
    int*   colv    = (int*)(ws + 600016);                // E ints
    float* h0      = (float*)(ws + 600016 + 3200000);    // N*64 floats
    float* pooled  = (float*)(ws + 600016 + 3200000 + 12800000); // G*64

    hipMemsetAsync(cnt, 0, 400000, stream);              // cnt + fill together
    hipMemsetAsync(pooled, 0, (size_t)G * HID * sizeof(float), stream);

    int eb = (E + 255) / 256;
    k_count<<<eb, 256, 0, stream>>>(dst, cnt, E);
    k_scan<<<1, 1024, 0, stream>>>(cnt, row_ptr, N);
    k_place<<<eb, 256, 0, stream>>>(src, dst, row_ptr, fill, colv, E);

    k_gmlp0<<<2048, 256, 0, stream>>>((const float2*)x, row_ptr, colv, eps0,
                                      w0a, b0a, w0b, b0b, h0, N);
    k_gmlp1<<<2048, 256, 0, stream>>>(h0, row_ptr, colv, eps1,
                                      w1a, b1a, w1b, b1b, batch, pooled, N);
    k_head<<<G, 64, 0, stream>>>(pooled, fcw, fcb, out);
}

// Round 3
// 424.057 us; speedup vs baseline: 5.2804x; 1.5893x over previous
//
#include <hip/hip_runtime.h>
#include <math.h>

#define IN_CH 128
#define HID 64
#define OUT_CH 10

typedef unsigned int uint32;
typedef unsigned short ushort16;

static __device__ inline ushort16 f2bf(float f) {
    uint32 u = __float_as_uint(f);
    u += 0x7fff + ((u >> 16) & 1);          // round-nearest-even
    return (ushort16)(u >> 16);
}
static __device__ inline float bf2f(ushort16 h) {
    return __uint_as_float(((uint32)h) << 16);
}

// ---------- CSR build: degree count ----------
__global__ __launch_bounds__(256) void k_count(
    const int* __restrict__ dst, int* __restrict__ cnt, int E)
{
    int e = blockIdx.x * 256 + threadIdx.x;
    if (e < E) atomicAdd(&cnt[dst[e]], 1);
}

// ---------- CSR build: exclusive scan cnt[N] -> row_ptr[N+1] ----------
__global__ __launch_bounds__(1024) void k_scan(
    const int* __restrict__ cnt, int* __restrict__ row_ptr, int N)
{
    __shared__ int lds[1024];
    int tid = threadIdx.x;
    int chunk = (N + 1023) >> 10;
    long start = (long)tid * chunk;
    int s = 0;
    for (int i = 0; i < chunk; i++) {
        long idx = start + i;
        if (idx < N) s += cnt[idx];
    }
    lds[tid] = s;
    __syncthreads();
    for (int off = 1; off < 1024; off <<= 1) {
        int t = (tid >= off) ? lds[tid - off] : 0;
        __syncthreads();
        lds[tid] += t;
        __syncthreads();
    }
    int run = lds[tid] - s;
    for (int i = 0; i < chunk; i++) {
        long idx = start + i;
        if (idx < N) { row_ptr[idx] = run; run += cnt[idx]; }
    }
    if (tid == 1023) row_ptr[N] = lds[1023];
}

// ---------- CSR build: place edges ----------
__global__ __launch_bounds__(256) void k_place(
    const int* __restrict__ src, const int* __restrict__ dst,
    const int* __restrict__ row_ptr, int* __restrict__ fill,
    int* __restrict__ col, int E)
{
    int e = blockIdx.x * 256 + threadIdx.x;
    if (e >= E) return;
    int d = dst[e];
    int pos = atomicAdd(&fill[d], 1);
    col[row_ptr[d] + pos] = src[e];
}

// ---------- dense GEMM: y[N,64](bf16) = x[N,128] @ w[128,64] ----------
__global__ __launch_bounds__(256) void k_lin0(
    const float4* __restrict__ x4, const float* __restrict__ w,
    ushort16* __restrict__ y, int N)
{
    __shared__ float lw[IN_CH * HID];     // 32 KB
    __shared__ float t[4][IN_CH];         // 2 KB
    int tid = threadIdx.x;
    for (int i = tid; i < IN_CH * HID; i += 256) lw[i] = w[i];
    int n = tid >> 6, c = tid & 63;
    __syncthreads();
    for (int g0 = blockIdx.x * 4; g0 < N; g0 += gridDim.x * 4) {
        if (tid < 128) {                  // 4 nodes x 32 float4 = 128
            int nn = tid >> 5, q = tid & 31;
            int node = g0 + nn;
            if (node < N) ((float4*)t)[nn * 32 + q] = x4[(long)node * 32 + q];
        }
        __syncthreads();
        float acc = 0.f;
        #pragma unroll
        for (int k = 0; k < IN_CH; k++) acc = fmaf(t[n][k], lw[k * HID + c], acc);
        int node = g0 + n;
        if (node < N) y[(long)node * HID + c] = f2bf(acc);
        __syncthreads();
    }
}

// ---------- dense GEMM: y[N,64](bf16) = h[N,64](bf16) @ w[64,64] ----------
__global__ __launch_bounds__(256) void k_lin1(
    const ushort16* __restrict__ h, const float* __restrict__ w,
    ushort16* __restrict__ y, int N)
{
    __shared__ float lw[HID * HID];       // 16 KB
    __shared__ float t[4][HID];
    int tid = threadIdx.x;
    for (int i = tid; i < HID * HID; i += 256) lw[i] = w[i];
    int n = tid >> 6, c = tid & 63;
    __syncthreads();
    for (int g0 = blockIdx.x * 4; g0 < N; g0 += gridDim.x * 4) {
        int node = g0 + n;
        if (node < N) t[n][c] = bf2f(h[(long)node * HID + c]);
        __syncthreads();
        float acc = 0.f;
        #pragma unroll
        for (int k = 0; k < HID; k++) acc = fmaf(t[n][k], lw[k * HID + c], acc);
        if (node < N) y[(long)node * HID + c] = f2bf(acc);
        __syncthreads();
    }
}

// ---------- gather + GIN epilogue: h0 = relu(relu((1+e)y + sum y[nbr] + ba) @ wb + bb)
__global__ __launch_bounds__(256) void k_agg0(
    const ushort16* __restrict__ y, const int* __restrict__ row_ptr,
    const int* __restrict__ col, const float* __restrict__ epsp,
    const float* __restrict__ ba, const float* __restrict__ wb,
    const float* __restrict__ bb, ushort16* __restrict__ h0, int N)
{
    __shared__ float lwb[HID * HID];      // 16 KB
    __shared__ float hbuf[4][HID];
    int tid = threadIdx.x;
    for (int i = tid; i < HID * HID; i += 256) lwb[i] = wb[i];
    float e = 1.f + epsp[0];
    int n = tid >> 6, c = tid & 63;
    float bias_a = ba[c], bias_b = bb[c];
    __syncthreads();
    for (int g0 = blockIdx.x * 4; g0 < N; g0 += gridDim.x * 4) {
        int node = g0 + n;
        float acc = bias_a;
        if (node < N) {
            int rs = row_ptr[node], re = row_ptr[node + 1];
            int j = rs;
            for (; j + 4 <= re; j += 4) {
                int s0 = col[j], s1 = col[j + 1], s2 = col[j + 2], s3 = col[j + 3];
                float v0 = bf2f(y[(long)s0 * HID + c]);
                float v1 = bf2f(y[(long)s1 * HID + c]);
                float v2 = bf2f(y[(long)s2 * HID + c]);
                float v3 = bf2f(y[(long)s3 * HID + c]);
                acc += (v0 + v1) + (v2 + v3);
            }
            for (; j < re; j++) acc += bf2f(y[(long)col[j] * HID + c]);
            acc += e * bf2f(y[(long)node * HID + c]);
        }
        hbuf[n][c] = fmaxf(acc, 0.f);
        __syncthreads();
        float a2 = bias_b;
        #pragma unroll
        for (int k = 0; k < HID; k++) a2 = fmaf(hbuf[n][k], lwb[k * HID + c], a2);
        if (node < N) h0[(long)node * HID + c] = f2bf(fmaxf(a2, 0.f));
        __syncthreads();
    }
}

// ---------- layer-1 gather + epilogue + pooling ----------
__global__ __launch_bounds__(256) void k_agg1(
    const ushort16* __restrict__ y, const int* __restrict__ row_ptr,
    const int* __restrict__ col, const float* __restrict__ epsp,
    const float* __restrict__ ba, const float* __restrict__ wb,
    const float* __restrict__ bb, const int* __restrict__ batch,
    float* __restrict__ pooled, int N)
{
    __shared__ float lwb[HID * HID];
    __shared__ float hbuf[4][HID];
    __shared__ float red[4][HID];
    int tid = threadIdx.x;
    for (int i = tid; i < HID * HID; i += 256) lwb[i] = wb[i];
    float e = 1.f + epsp[0];
    int n = tid >> 6, c = tid & 63;
    float bias_a = ba[c], bias_b = bb[c];
    __syncthreads();
    for (int g0 = blockIdx.x * 4; g0 < N; g0 += gridDim.x * 4) {
        int node = g0 + n;
        float acc = bias_a;
        if (node < N) {
            int rs = row_ptr[node], re = row_ptr[node + 1];
            int j = rs;
            for (; j + 4 <= re; j += 4) {
                int s0 = col[j], s1 = col[j + 1], s2 = col[j + 2], s3 = col[j + 3];
                float v0 = bf2f(y[(long)s0 * HID + c]);
                float v1 = bf2f(y[(long)s1 * HID + c]);
                float v2 = bf2f(y[(long)s2 * HID + c]);
                float v3 = bf2f(y[(long)s3 * HID + c]);
                acc += (v0 + v1) + (v2 + v3);
            }
            for (; j < re; j++) acc += bf2f(y[(long)col[j] * HID + c]);
            acc += e * bf2f(y[(long)node * HID + c]);
        }
        hbuf[n][c] = fmaxf(acc, 0.f);
        __syncthreads();
        float a2 = bias_b;
        #pragma unroll
        for (int k = 0; k < HID; k++) a2 = fmaf(hbuf[n][k], lwb[k * HID + c], a2);
        red[n][c] = (node < N) ? fmaxf(a2, 0.f) : 0.f;
        __syncthreads();
        if (n == 0 && g0 < N) {
            int nv = min(4, N - g0);
            int b0 = batch[g0], bl = batch[g0 + nv - 1];
            if (b0 == bl) {
                float s = red[0][c];
                for (int nn = 1; nn < nv; nn++) s += red[nn][c];
                atomicAdd(&pooled[(long)b0 * HID + c], s);
            } else {
                for (int nn = 0; nn < nv; nn++)
                    atomicAdd(&pooled[(long)batch[g0 + nn] * HID + c], red[nn][c]);
            }
        }
        __syncthreads();
    }
}

// ---------- head: logits = pooled@fcw+fcb; log_softmax ----------
__global__ __launch_bounds__(64) void k_head(
    const float* __restrict__ pooled, const float* __restrict__ fcw,
    const float* __restrict__ fcb, float* __restrict__ out)
{
    int g = blockIdx.x;
    int l = threadIdx.x;
    float logit = -INFINITY;
    if (l < OUT_CH) {
        float acc = fcb[l];
        #pragma unroll
        for (int k = 0; k < HID; k++)
            acc = fmaf(pooled[g * HID + k], fcw[k * OUT_CH + l], acc);
        logit = acc;
    }
    float m = logit;
    #pragma unroll
    for (int off = 32; off; off >>= 1) m = fmaxf(m, __shfl_xor(m, off));
    float ex = (l < OUT_CH) ? expf(logit - m) : 0.0f;
    float s = ex;
    #pragma unroll
    for (int off = 32; off; off >>= 1) s += __shfl_xor(s, off);
    if (l < OUT_CH) out[g * OUT_CH + l] = logit - m - logf(s);
}

extern "C" void kernel_launch(void* const* d_in, const int* in_sizes, int n_in,
                              void* d_out, int out_size, void* d_ws, size_t ws_size,
                              hipStream_t stream) {
    const float* x    = (const float*)d_in[0];
    const int*   ei   = (const int*)d_in[1];
    const int*   batch= (const int*)d_in[2];
    const float* eps0 = (const float*)d_in[3];
    const float* w0a  = (const float*)d_in[4];
    const float* b0a  = (const float*)d_in[5];
    const float* w0b  = (const float*)d_in[6];
    const float* b0b  = (const float*)d_in[7];
    const float* eps1 = (const float*)d_in[8];
    const float* w1a  = (const float*)d_in[9];
    const float* b1a  = (const float*)d_in[10];
    const float* w1b  = (const float*)d_in[11];
    const float* b1b  = (const float*)d_in[12];
    const float* fcw  = (const float*)d_in[13];
    const float* fcb  = (const float*)d_in[14];
    float* out = (float*)d_out;

    const int N = in_sizes[0] / IN_CH;       // 50000
    const int E = in_sizes[1] / 2;           // 800000
    const int G = out_size / OUT_CH;         // 512
    const int* src = ei;
    const int* dst = ei + E;

    // workspace layout (bytes)
    // [0, 200064)            row_ptr  (N+1 ints)
    // [200064, 3400064)      col      (E ints)
    // [3400064, 9800064)     y0 / y1  (N*64 bf16)
    // [9800064, 16200064)    h0       (N*64 bf16)  -- first 400 KB doubles as cnt+fill
    // [16200064, 16331136)   pooled   (G*64 fp32)
    char* ws = (char*)d_ws;
    int*       row_ptr = (int*)(ws);
    int*       colv    = (int*)(ws + 200064);
    ushort16*  y01     = (ushort16*)(ws + 3400064);
    ushort16*  h0      = (ushort16*)(ws + 9800064);
    int*       cnt     = (int*)(ws + 9800064);
    int*       fill    = (int*)(ws + 10000064);
    float*     pooled  = (float*)(ws + 16200064);

    hipMemsetAsync(cnt, 0, 400000, stream);              // cnt + fill
    hipMemsetAsync(pooled, 0, (size_t)G * HID * sizeof(float), stream);

    int eb = (E + 255) / 256;
    k_count<<<eb, 256, 0, stream>>>(dst, cnt, E);
    k_scan<<<1, 1024, 0, stream>>>(cnt, row_ptr, N);
    k_place<<<eb, 256, 0, stream>>>(src, dst, row_ptr, fill, colv, E);

    k_lin0<<<2048, 256, 0, stream>>>((const float4*)x, w0a, y01, N);
    k_agg0<<<2048, 256, 0, stream>>>(y01, row_ptr, colv, eps0, b0a, w0b, b0b, h0, N);
    k_lin1<<<2048, 256, 0, stream>>>(h0, w1a, y01, N);
    k_agg1<<<2048, 256, 0, stream>>>(y01, row_ptr, colv, eps1, b1a, w1b, b1b,
                                     batch, pooled, N);
    k_head<<<G, 64, 0, stream>>>(pooled, fcw, fcb, out);
}

// Round 4
// 345.660 us; speedup vs baseline: 6.4780x; 1.2268x over previous
//
#include <hip/hip_runtime.h>
#include <math.h>

#define IN_CH 128
#define HID 64
#define OUT_CH 10

typedef unsigned int uint32;
typedef unsigned short bf16u;

static __device__ inline bf16u f2bf(float f) {
    uint32 u = __float_as_uint(f);
    u += 0x7fff + ((u >> 16) & 1);          // round-nearest-even
    return (bf16u)(u >> 16);
}
static __device__ inline float bf2f(bf16u h) {
    return __uint_as_float(((uint32)h) << 16);
}

// ---------- CSR build: degree count ----------
__global__ __launch_bounds__(256) void k_count(
    const int* __restrict__ dst, int* __restrict__ cnt, int E)
{
    int e = blockIdx.x * 256 + threadIdx.x;
    if (e < E) atomicAdd(&cnt[dst[e]], 1);
}

// ---------- scan stage 1: per-block (1024 elems) partial sums ----------
__global__ __launch_bounds__(256) void k_scan1(
    const int* __restrict__ cnt, int* __restrict__ partials, int N)
{
    __shared__ int red[256];
    int tid = threadIdx.x;
    long base = (long)blockIdx.x * 1024 + tid * 4;
    int s = 0;
    #pragma unroll
    for (int i = 0; i < 4; i++) { long idx = base + i; if (idx < N) s += cnt[idx]; }
    red[tid] = s;
    __syncthreads();
    for (int off = 128; off; off >>= 1) {
        if (tid < off) red[tid] += red[tid + off];
        __syncthreads();
    }
    if (tid == 0) partials[blockIdx.x] = red[0];
}

// ---------- scan stage 2: one wave scans the partials -> exclusive offsets ----
__global__ __launch_bounds__(64) void k_scan2(
    const int* __restrict__ partials, int* __restrict__ poff, int nch)
{
    int lane = threadIdx.x;
    int carry = 0;
    for (int base = 0; base < nch; base += 64) {
        int i = base + lane;
        int v = (i < nch) ? partials[i] : 0;
        int incl = v;
        #pragma unroll
        for (int off = 1; off < 64; off <<= 1) {
            int t = __shfl_up(incl, off);
            if (lane >= off) incl += t;
        }
        if (i < nch) poff[i] = carry + incl - v;
        carry += __shfl(incl, 63);
    }
}

// ---------- scan stage 3: block-local exclusive scan + offset -> row_ptr ----
__global__ __launch_bounds__(256) void k_scan3(
    const int* __restrict__ cnt, const int* __restrict__ poff,
    int* __restrict__ row_ptr, int N, int E)
{
    __shared__ int lds[256];
    int tid = threadIdx.x;
    long base = (long)blockIdx.x * 1024 + tid * 4;
    int v[4]; int s = 0;
    #pragma unroll
    for (int i = 0; i < 4; i++) {
        long idx = base + i;
        v[i] = (idx < N) ? cnt[idx] : 0;
        s += v[i];
    }
    lds[tid] = s;
    __syncthreads();
    for (int off = 1; off < 256; off <<= 1) {
        int t = (tid >= off) ? lds[tid - off] : 0;
        __syncthreads();
        lds[tid] += t;
        __syncthreads();
    }
    int run = poff[blockIdx.x] + lds[tid] - s;
    #pragma unroll
    for (int i = 0; i < 4; i++) {
        long idx = base + i;
        if (idx < N) row_ptr[idx] = run;
        run += v[i];
    }
    if (blockIdx.x == 0 && tid == 0) row_ptr[N] = E;
}

// ---------- CSR build: place edges ----------
__global__ __launch_bounds__(256) void k_place(
    const int* __restrict__ src, const int* __restrict__ dst,
    const int* __restrict__ row_ptr, int* __restrict__ fill,
    int* __restrict__ col, int E)
{
    int e = blockIdx.x * 256 + threadIdx.x;
    if (e >= E) return;
    int d = dst[e];
    int pos = atomicAdd(&fill[d], 1);
    col[row_ptr[d] + pos] = src[e];
}

// ---------- dense GEMM: y0[N,64](bf16) = x[N,128] @ w0a[128,64] ----------
__global__ __launch_bounds__(256) void k_lin0(
    const float4* __restrict__ x4, const float* __restrict__ w,
    bf16u* __restrict__ y, int N)
{
    __shared__ float lw[IN_CH * HID];     // 32 KB
    __shared__ float t[4][IN_CH];         // 2 KB
    int tid = threadIdx.x;
    for (int i = tid; i < IN_CH * HID; i += 256) lw[i] = w[i];
    int n = tid >> 6, c = tid & 63;
    __syncthreads();
    for (int g0 = blockIdx.x * 4; g0 < N; g0 += gridDim.x * 4) {
        if (tid < 128) {                  // 4 nodes x 32 float4
            int nn = tid >> 5, q = tid & 31;
            int node = g0 + nn;
            if (node < N) ((float4*)t)[nn * 32 + q] = x4[(long)node * 32 + q];
        }
        __syncthreads();
        float acc = 0.f;
        #pragma unroll
        for (int k = 0; k < IN_CH; k++) acc = fmaf(t[n][k], lw[k * HID + c], acc);
        int node = g0 + n;
        if (node < N) y[(long)node * HID + c] = f2bf(acc);
        __syncthreads();
    }
}

// ---------- layer-0 gather + MLP-b + fused lin1:
// y1 = ( relu( relu((1+e)y0 + sum y0[nbr] + b0a) @ w0b + b0b ) ) @ w1a
__global__ __launch_bounds__(256) void k_agg0f(
    const bf16u* __restrict__ y, const int* __restrict__ row_ptr,
    const int* __restrict__ col, const float* __restrict__ epsp,
    const float* __restrict__ ba, const float* __restrict__ wb,
    const float* __restrict__ bb, const float* __restrict__ w1a,
    bf16u* __restrict__ y1, int N)
{
    __shared__ float lwb[HID * HID];      // 16 KB
    __shared__ float lw1[HID * HID];      // 16 KB
    __shared__ float hbuf[4][HID];
    __shared__ float tbuf[4][HID];
    int tid = threadIdx.x;
    for (int i = tid; i < HID * HID; i += 256) { lwb[i] = wb[i]; lw1[i] = w1a[i]; }
    float e = 1.f + epsp[0];
    int n = tid >> 6, c = tid & 63;
    float bias_a = ba[c], bias_b = bb[c];
    __syncthreads();
    for (int g0 = blockIdx.x * 4; g0 < N; g0 += gridDim.x * 4) {
        int node = g0 + n;
        float acc = bias_a;
        if (node < N) {
            int rs = row_ptr[node], re = row_ptr[node + 1];
            int j = rs;
            for (; j + 4 <= re; j += 4) {
                int s0 = col[j], s1 = col[j + 1], s2 = col[j + 2], s3 = col[j + 3];
                float v0 = bf2f(y[(long)s0 * HID + c]);
                float v1 = bf2f(y[(long)s1 * HID + c]);
                float v2 = bf2f(y[(long)s2 * HID + c]);
                float v3 = bf2f(y[(long)s3 * HID + c]);
                acc += (v0 + v1) + (v2 + v3);
            }
            for (; j < re; j++) acc += bf2f(y[(long)col[j] * HID + c]);
            acc += e * bf2f(y[(long)node * HID + c]);
        }
        hbuf[n][c] = fmaxf(acc, 0.f);
        __syncthreads();
        float a2 = bias_b;
        #pragma unroll
        for (int k = 0; k < HID; k++) a2 = fmaf(hbuf[n][k], lwb[k * HID + c], a2);
        tbuf[n][c] = fmaxf(a2, 0.f);
        __syncthreads();
        float a3 = 0.f;
        #pragma unroll
        for (int k = 0; k < HID; k++) a3 = fmaf(tbuf[n][k], lw1[k * HID + c], a3);
        if (node < N) y1[(long)node * HID + c] = f2bf(a3);
        __syncthreads();
    }
}

// ---------- layer-1 gather + MLP-b + pooling ----------
__global__ __launch_bounds__(256) void k_agg1(
    const bf16u* __restrict__ y, const int* __restrict__ row_ptr,
    const int* __restrict__ col, const float* __restrict__ epsp,
    const float* __restrict__ ba, const float* __restrict__ wb,
    const float* __restrict__ bb, const int* __restrict__ batch,
    float* __restrict__ pooled, int N)
{
    __shared__ float lwb[HID * HID];
    __shared__ float hbuf[4][HID];
    __shared__ float red[4][HID];
    int tid = threadIdx.x;
    for (int i = tid; i < HID * HID; i += 256) lwb[i] = wb[i];
    float e = 1.f + epsp[0];
    int n = tid >> 6, c = tid & 63;
    float bias_a = ba[c], bias_b = bb[c];
    __syncthreads();
    for (int g0 = blockIdx.x * 4; g0 < N; g0 += gridDim.x * 4) {
        int node = g0 + n;
        float acc = bias_a;
        if (node < N) {
            int rs = row_ptr[node], re = row_ptr[node + 1];
            int j = rs;
            for (; j + 4 <= re; j += 4) {
                int s0 = col[j], s1 = col[j + 1], s2 = col[j + 2], s3 = col[j + 3];
                float v0 = bf2f(y[(long)s0 * HID + c]);
                float v1 = bf2f(y[(long)s1 * HID + c]);
                float v2 = bf2f(y[(long)s2 * HID + c]);
                float v3 = bf2f(y[(long)s3 * HID + c]);
                acc += (v0 + v1) + (v2 + v3);
            }
            for (; j < re; j++) acc += bf2f(y[(long)col[j] * HID + c]);
            acc += e * bf2f(y[(long)node * HID + c]);
        }
        hbuf[n][c] = fmaxf(acc, 0.f);
        __syncthreads();
        float a2 = bias_b;
        #pragma unroll
        for (int k = 0; k < HID; k++) a2 = fmaf(hbuf[n][k], lwb[k * HID + c], a2);
        red[n][c] = (node < N) ? fmaxf(a2, 0.f) : 0.f;
        __syncthreads();
        if (n == 0 && g0 < N) {
            int nv = min(4, N - g0);
            int b0 = batch[g0], bl = batch[g0 + nv - 1];
            if (b0 == bl) {
                float s = red[0][c];
                for (int nn = 1; nn < nv; nn++) s += red[nn][c];
                atomicAdd(&pooled[(long)b0 * HID + c], s);
            } else {
                for (int nn = 0; nn < nv; nn++)
                    atomicAdd(&pooled[(long)batch[g0 + nn] * HID + c], red[nn][c]);
            }
        }
        __syncthreads();
    }
}

// ---------- head: logits = pooled@fcw+fcb; log_softmax ----------
__global__ __launch_bounds__(64) void k_head(
    const float* __restrict__ pooled, const float* __restrict__ fcw,
    const float* __restrict__ fcb, float* __restrict__ out)
{
    int g = blockIdx.x;
    int l = threadIdx.x;
    float logit = -INFINITY;
    if (l < OUT_CH) {
        float acc = fcb[l];
        #pragma unroll
        for (int k = 0; k < HID; k++)
            acc = fmaf(pooled[g * HID + k], fcw[k * OUT_CH + l], acc);
        logit = acc;
    }
    float m = logit;
    #pragma unroll
    for (int off = 32; off; off >>= 1) m = fmaxf(m, __shfl_xor(m, off));
    float ex = (l < OUT_CH) ? expf(logit - m) : 0.0f;
    float s = ex;
    #pragma unroll
    for (int off = 32; off; off >>= 1) s += __shfl_xor(s, off);
    if (l < OUT_CH) out[g * OUT_CH + l] = logit - m - logf(s);
}

extern "C" void kernel_launch(void* const* d_in, const int* in_sizes, int n_in,
                              void* d_out, int out_size, void* d_ws, size_t ws_size,
                              hipStream_t stream) {
    const float* x    = (const float*)d_in[0];
    const int*   ei   = (const int*)d_in[1];
    const int*   batch= (const int*)d_in[2];
    const float* eps0 = (const float*)d_in[3];
    const float* w0a  = (const float*)d_in[4];
    const float* b0a  = (const float*)d_in[5];
    const float* w0b  = (const float*)d_in[6];
    const float* b0b  = (const float*)d_in[7];
    const float* eps1 = (const float*)d_in[8];
    const float* w1a  = (const float*)d_in[9];
    const float* b1a  = (const float*)d_in[10];
    const float* w1b  = (const float*)d_in[11];
    const float* b1b  = (const float*)d_in[12];
    const float* fcw  = (const float*)d_in[13];
    const float* fcb  = (const float*)d_in[14];
    float* out = (float*)d_out;

    const int N = in_sizes[0] / IN_CH;       // 50000
    const int E = in_sizes[1] / 2;           // 800000
    const int G = out_size / OUT_CH;         // 512
    const int* src = ei;
    const int* dst = ei + E;

    // workspace layout (bytes):
    // [0, 200064)             row_ptr  (N+1 ints)
    // [200064, 3400064)       col      (E ints)
    // [3400064, 9800064)      y0       (N*64 bf16)
    // [9800064, 16200064)     y1       (N*64 bf16)
    //    cnt      @ 9800064   (N ints)      -- overlay, dead before y1 written
    //    fill     @ 10000128  (N ints)
    //    partials @ 10200192  (256 B)
    //    poff     @ 10200448  (256 B)
    // [16200064, 16331136)    pooled   (G*64 fp32)
    char* ws = (char*)d_ws;
    int*    row_ptr  = (int*)(ws);
    int*    colv     = (int*)(ws + 200064);
    bf16u*  y0       = (bf16u*)(ws + 3400064);
    bf16u*  y1       = (bf16u*)(ws + 9800064);
    int*    cnt      = (int*)(ws + 9800064);
    int*    fill     = (int*)(ws + 10000128);
    int*    partials = (int*)(ws + 10200192);
    int*    poff     = (int*)(ws + 10200448);
    float*  pooled   = (float*)(ws + 16200064);

    hipMemsetAsync(cnt, 0, 400128, stream);     // covers cnt + fill
    hipMemsetAsync(pooled, 0, (size_t)G * HID * sizeof(float), stream);

    int eb = (E + 255) / 256;
    int nch = (N + 1023) / 1024;                // scan chunks (49)
    k_count<<<eb, 256, 0, stream>>>(dst, cnt, E);
    k_scan1<<<nch, 256, 0, stream>>>(cnt, partials, N);
    k_scan2<<<1, 64, 0, stream>>>(partials, poff, nch);
    k_scan3<<<nch, 256, 0, stream>>>(cnt, poff, row_ptr, N, E);
    k_place<<<eb, 256, 0, stream>>>(src, dst, row_ptr, fill, colv, E);

    k_lin0<<<2048, 256, 0, stream>>>((const float4*)x, w0a, y0, N);
    k_agg0f<<<2048, 256, 0, stream>>>(y0, row_ptr, colv, eps0, b0a, w0b, b0b,
                                      w1a, y1, N);
    k_agg1<<<2048, 256, 0, stream>>>(y1, row_ptr, colv, eps1, b1a, w1b, b1b,
                                     batch, pooled, N);
    k_head<<<G, 64, 0, stream>>>(pooled, fcw, fcb, out);
}